// Round 1
// baseline (161.528 us; speedup 1.0000x reference)
//
#include <hip/hip_runtime.h>
#include <math.h>

#define PI_F 3.14159265358979323846f

struct c2 { float x, y; };
__device__ __forceinline__ c2 cmul(c2 a, c2 b){ return c2{a.x*b.x - a.y*b.y, a.x*b.y + a.y*b.x}; }
__device__ __forceinline__ c2 cadd(c2 a, c2 b){ return c2{a.x+b.x, a.y+b.y}; }

__device__ __forceinline__ void rot2(c2 &a, c2 &b, c2 g00, c2 g01, c2 g10, c2 g11) {
  c2 na = cadd(cmul(g00,a), cmul(g01,b));
  c2 nb = cadd(cmul(g10,a), cmul(g11,b));
  a = na; b = nb;
}

__device__ __forceinline__ void mk_u3(float th, float ph, float la,
                                      c2 &g00, c2 &g01, c2 &g10, c2 &g11) {
  float ch = cosf(0.5f*th), sh = sinf(0.5f*th);
  float cl = cosf(la), sl = sinf(la);
  float cp = cosf(ph), sp = sinf(ph);
  float cpl = cp*cl - sp*sl, spl = sp*cl + cp*sl;
  g00 = c2{ch, 0.f};
  g01 = c2{-cl*sh, -sl*sh};
  g10 = c2{cp*sh, sp*sh};
  g11 = c2{cpl*ch, spl*ch};
}

template<int MA, int MB>
__device__ __forceinline__ void apply2q(c2 psi[16], const c2 M[16]) {
#pragma unroll
  for (int r = 0; r < 16; ++r) {
    if (r & (MA | MB)) continue;
    c2 a = psi[r], b = psi[r|MB], c = psi[r|MA], d = psi[r|MA|MB];
    psi[r]        = cadd(cadd(cmul(M[0],a),  cmul(M[1],b)),  cadd(cmul(M[2],c),  cmul(M[3],d)));
    psi[r|MB]     = cadd(cadd(cmul(M[4],a),  cmul(M[5],b)),  cadd(cmul(M[6],c),  cmul(M[7],d)));
    psi[r|MA]     = cadd(cadd(cmul(M[8],a),  cmul(M[9],b)),  cadd(cmul(M[10],c), cmul(M[11],d)));
    psi[r|MA|MB]  = cadd(cadd(cmul(M[12],a), cmul(M[13],b)), cadd(cmul(M[14],c), cmul(M[15],d)));
  }
}

// ---------------- K0: build A_w = Re(U^dag Z_w U), 4 x 16 x 16 ----------------
__global__ __launch_bounds__(256) void k_qmat(const float* __restrict__ qw_u3,
                                              const float* __restrict__ qw_ang,
                                              float* __restrict__ A) {
  __shared__ c2 SU[2][16];
  __shared__ float Ur[16*17], Ui[16*17];
  int t = threadIdx.x;
  if (t < 8) {
    int L = t >> 2, col = t & 3;
    c2 s[4];
#pragma unroll
    for (int i = 0; i < 4; ++i) s[i] = c2{(i==col)?1.f:0.f, 0.f};
    const float* u = qw_u3 + 12*L;
    const float* g = qw_ang + 3*L;
    c2 g00,g01,g10,g11;
    mk_u3(u[0],u[1],u[2], g00,g01,g10,g11);             // u3s[0] on a (mask 2)
    rot2(s[0],s[2], g00,g01,g10,g11); rot2(s[1],s[3], g00,g01,g10,g11);
    mk_u3(u[3],u[4],u[5], g00,g01,g10,g11);             // u3s[1] on b (mask 1)
    rot2(s[0],s[1], g00,g01,g10,g11); rot2(s[2],s[3], g00,g01,g10,g11);
    { c2 tmp = s[2]; s[2] = s[3]; s[3] = tmp; }          // CNOT a->b
    { float c = cosf(0.5f*g[0]), sn = sinf(0.5f*g[0]);
      c2 r00{c,0.f}, r01{-sn,0.f}, r10{sn,0.f}, r11{c,0.f};
      rot2(s[0],s[2], r00,r01,r10,r11); rot2(s[1],s[3], r00,r01,r10,r11); } // RY(angs0) on a
    { float c = cosf(0.5f*g[1]), sn = sinf(0.5f*g[1]);
      c2 e0{c,-sn}, e1{c,sn};
      s[0]=cmul(s[0],e0); s[1]=cmul(s[1],e1); s[2]=cmul(s[2],e0); s[3]=cmul(s[3],e1); } // RZ(angs1) on b
    { c2 tmp = s[1]; s[1] = s[3]; s[3] = tmp; }          // CNOT b->a
    { float c = cosf(0.5f*g[2]), sn = sinf(0.5f*g[2]);
      c2 r00{c,0.f}, r01{-sn,0.f}, r10{sn,0.f}, r11{c,0.f};
      rot2(s[0],s[2], r00,r01,r10,r11); rot2(s[1],s[3], r00,r01,r10,r11); } // RY(angs2) on a
    { c2 tmp = s[2]; s[2] = s[3]; s[3] = tmp; }          // CNOT a->b
    mk_u3(u[6],u[7],u[8], g00,g01,g10,g11);             // u3s[2] on a
    rot2(s[0],s[2], g00,g01,g10,g11); rot2(s[1],s[3], g00,g01,g10,g11);
    mk_u3(u[9],u[10],u[11], g00,g01,g10,g11);           // u3s[3] on b
    rot2(s[0],s[1], g00,g01,g10,g11); rot2(s[2],s[3], g00,g01,g10,g11);
#pragma unroll
    for (int k = 0; k < 4; ++k) SU[L][k*4 + col] = s[k];
  }
  __syncthreads();
  if (t < 16) {
    c2 psi[16];
#pragma unroll
    for (int i = 0; i < 16; ++i) psi[i] = c2{(i==t)?1.f:0.f, 0.f};
#pragma unroll
    for (int l = 0; l < 2; ++l) {
      c2 M[16];
#pragma unroll
      for (int k = 0; k < 16; ++k) M[k] = SU[l][k];
      apply2q<8,4>(psi, M);   // pair (0,1)
      apply2q<4,2>(psi, M);   // pair (1,2)
      apply2q<2,1>(psi, M);   // pair (2,3)
      apply2q<1,8>(psi, M);   // pair (3,0)
    }
#pragma unroll
    for (int k = 0; k < 16; ++k) { Ur[k*17+t] = psi[k].x; Ui[k*17+t] = psi[k].y; }
  }
  __syncthreads();
  {
    int i = t >> 4, j = t & 15;
    float a0=0.f,a1=0.f,a2=0.f,a3=0.f;
#pragma unroll
    for (int k = 0; k < 16; ++k) {
      float pr = Ur[k*17+i]*Ur[k*17+j] + Ui[k*17+i]*Ui[k*17+j];
      a0 += ((k>>3)&1) ? -pr : pr;
      a1 += ((k>>2)&1) ? -pr : pr;
      a2 += ((k>>1)&1) ? -pr : pr;
      a3 += ( k     &1) ? -pr : pr;
    }
    A[0*256 + t] = a0; A[1*256 + t] = a1; A[2*256 + t] = a2; A[3*256 + t] = a3;
  }
}

// ---------------- Ktrans: transpose FC weights for coalesced reads ----------------
__global__ __launch_bounds__(256) void k_trans(const float* __restrict__ w1a, const float* __restrict__ w1b,
                                               const float* __restrict__ w2a, const float* __restrict__ w2b,
                                               float* __restrict__ wt) {
  int id = blockIdx.x*256 + threadIdx.x;
  if (id < 16384) { int j = id >> 6, o = id & 63;  wt[id] = w1a[o*256 + j]; return; }
  id -= 16384;
  if (id < 8192)  { int j = id >> 7, o = id & 127; wt[16384 + id] = w1b[o*64 + j]; return; }
  id -= 8192;
  if (id < 8192)  { int j = id >> 6, o = id & 63;  wt[24576 + id] = w2a[o*128 + j]; return; }
  id -= 8192;
  if (id < 640)   { int j = id / 10, o = id % 10;  wt[32768 + id] = w2b[o*64 + j]; }
}

// ---------------- K1: conv1(3->64) + relu + maxpool2, per-image block ----------------
__global__ __launch_bounds__(256) void k_conv1(const float* __restrict__ x, const float* __restrict__ w,
                                               const float* __restrict__ bias, float* __restrict__ h1) {
  __shared__ float xs[3*32*32];
  int b = blockIdx.x, tid = threadIdx.x;
  const float4* xsrc = (const float4*)(x + (size_t)b*3072);
  float4* xd = (float4*)xs;
#pragma unroll
  for (int k = 0; k < 3; ++k) xd[tid + k*256] = xsrc[tid + k*256];
  __syncthreads();
  int y = tid >> 4, xo = tid & 15;
  int y2 = y*2, x2 = xo*2;
  float in[3][4][4];
#pragma unroll
  for (int c = 0; c < 3; ++c)
#pragma unroll
    for (int ky = 0; ky < 4; ++ky) {
      int iy = y2 + ky - 1;
      bool vy = ((unsigned)iy < 32u);
      int iyc = vy ? iy : 0;
#pragma unroll
      for (int kx = 0; kx < 4; ++kx) {
        int ix = x2 + kx - 1;
        bool v = vy && ((unsigned)ix < 32u);
        int ixc = ((unsigned)ix < 32u) ? ix : 0;
        float val = xs[c*1024 + iyc*32 + ixc];
        in[c][ky][kx] = v ? val : 0.f;
      }
    }
  float* out = h1 + (size_t)b*16384 + tid;
  for (int oc = 0; oc < 64; ++oc) {
    float bz = bias[oc];
    float a00=bz, a01=bz, a10=bz, a11=bz;
    const float* wp = w + oc*27;
#pragma unroll
    for (int c = 0; c < 3; ++c)
#pragma unroll
      for (int ky = 0; ky < 3; ++ky)
#pragma unroll
        for (int kx = 0; kx < 3; ++kx) {
          float wv = wp[c*9 + ky*3 + kx];
          a00 = fmaf(wv, in[c][ky  ][kx  ], a00);
          a01 = fmaf(wv, in[c][ky  ][kx+1], a01);
          a10 = fmaf(wv, in[c][ky+1][kx  ], a10);
          a11 = fmaf(wv, in[c][ky+1][kx+1], a11);
        }
    float m = fmaxf(fmaxf(a00,a01), fmaxf(a10,a11));
    out[oc*256] = fmaxf(m, 0.f);
  }
}

// ---------------- K2: conv2(64->16) + relu + maxpool2, per-image block ----------------
__global__ __launch_bounds__(256) void k_conv2(const float* __restrict__ h1, const float* __restrict__ w,
                                               const float* __restrict__ bias, float* __restrict__ h2) {
  __shared__ float hs[64*288];          // [ic][16 rows][18 cols], col 0 & 17 zero
  int b = blockIdx.x, tid = threadIdx.x;
  for (int r = tid; r < 1024; r += 256) {
    int ic = r >> 4, iy = r & 15;
    hs[ic*288 + iy*18 + 0]  = 0.f;
    hs[ic*288 + iy*18 + 17] = 0.f;
  }
  const float4* src = (const float4*)(h1 + (size_t)b*16384);
#pragma unroll
  for (int k = 0; k < 16; ++k) {
    float4 v = src[tid + k*256];
    int e = 4*(tid + k*256);
    int ic = e >> 8, iy = (e >> 4) & 15, ix = e & 15;
    float* d = &hs[ic*288 + iy*18 + ix + 1];
    d[0]=v.x; d[1]=v.y; d[2]=v.z; d[3]=v.w;
  }
  __syncthreads();
  int pos = tid & 63;
  int grp = __builtin_amdgcn_readfirstlane((int)(tid >> 6));  // wave-uniform -> scalar weight loads
  int y = pos >> 3, xo = pos & 7;
  int y2 = 2*y, x2 = 2*xo;
  int oc0 = grp*4;
  float acc[4][4];
#pragma unroll
  for (int o = 0; o < 4; ++o) {
    float bz = bias[oc0+o];
    acc[o][0]=bz; acc[o][1]=bz; acc[o][2]=bz; acc[o][3]=bz;
  }
  for (int ic = 0; ic < 64; ++ic) {
    float in[4][4];
#pragma unroll
    for (int ky = 0; ky < 4; ++ky) {
      int iy = y2 + ky - 1;
      bool v = ((unsigned)iy < 16u);
      int iyc = v ? iy : 0;
      const float* rp = &hs[ic*288 + iyc*18 + x2];
      float2 p0 = *(const float2*)rp;
      float2 p1 = *(const float2*)(rp+2);
      in[ky][0] = v ? p0.x : 0.f; in[ky][1] = v ? p0.y : 0.f;
      in[ky][2] = v ? p1.x : 0.f; in[ky][3] = v ? p1.y : 0.f;
    }
    const float* wp = w + (oc0*64 + ic)*9;
#pragma unroll
    for (int o = 0; o < 4; ++o) {
      const float* wpo = wp + o*576;
#pragma unroll
      for (int ky = 0; ky < 3; ++ky)
#pragma unroll
        for (int kx = 0; kx < 3; ++kx) {
          float wv = wpo[ky*3+kx];
          acc[o][0] = fmaf(wv, in[ky  ][kx  ], acc[o][0]);
          acc[o][1] = fmaf(wv, in[ky  ][kx+1], acc[o][1]);
          acc[o][2] = fmaf(wv, in[ky+1][kx  ], acc[o][2]);
          acc[o][3] = fmaf(wv, in[ky+1][kx+1], acc[o][3]);
        }
    }
  }
  float* out = h2 + (size_t)b*1024;
#pragma unroll
  for (int o = 0; o < 4; ++o) {
    float m = fmaxf(fmaxf(acc[o][0],acc[o][1]), fmaxf(acc[o][2],acc[o][3]));
    out[(oc0+o)*64 + pos] = fmaxf(m, 0.f);
  }
}

// ------- K3: conv3(16->4) + leaky + sigmoid*pi -> (cos,sin) of half-angles -------
__global__ __launch_bounds__(256) void k_conv3(const float* __restrict__ h2, const float* __restrict__ w,
                                               const float* __restrict__ bias, float* __restrict__ cs) {
  __shared__ float h3s[4*1600];         // 4 images x [16 ic][10][10] fully zero-padded
  int b4 = blockIdx.x*4, tid = threadIdx.x;
  for (int i = tid; i < 6400; i += 256) h3s[i] = 0.f;
  __syncthreads();
  int img = tid >> 6, lane = tid & 63;
  const float4* src = (const float4*)(h2 + (size_t)(b4+img)*1024);
#pragma unroll
  for (int k = 0; k < 4; ++k) {
    float4 v = src[lane + k*64];
    int e = 4*(lane + k*64);
    int ic = e >> 6, iy = (e >> 3) & 7, ix = e & 7;
    float* d = &h3s[img*1600 + ic*100 + (iy+1)*10 + ix + 1];
    d[0]=v.x; d[1]=v.y; d[2]=v.z; d[3]=v.w;
  }
  __syncthreads();
  int y = lane >> 3, xo = lane & 7;
  float acc[4];
#pragma unroll
  for (int o = 0; o < 4; ++o) acc[o] = bias[o];
  for (int ic = 0; ic < 16; ++ic) {
    float in[3][3];
#pragma unroll
    for (int ky = 0; ky < 3; ++ky)
#pragma unroll
      for (int kx = 0; kx < 3; ++kx)
        in[ky][kx] = h3s[img*1600 + ic*100 + (y+ky)*10 + (xo+kx)];
#pragma unroll
    for (int o = 0; o < 4; ++o) {
      const float* wp = w + (o*16 + ic)*9;
#pragma unroll
      for (int ky = 0; ky < 3; ++ky)
#pragma unroll
        for (int kx = 0; kx < 3; ++kx)
          acc[o] = fmaf(wp[ky*3+kx], in[ky][kx], acc[o]);
    }
  }
  float cv[4], sv[4];
#pragma unroll
  for (int o = 0; o < 4; ++o) {
    float v = acc[o];
    float l = v > 0.f ? v : 0.01f*v;
    float sg = 1.f/(1.f + expf(-l));
    float ha = sg * (0.5f*PI_F);
    __sincosf(ha, &sv[o], &cv[o]);
  }
  size_t p = (size_t)(b4+img)*64 + lane;
  float4* dst = (float4*)(cs + p*8);
  dst[0] = make_float4(cv[0], sv[0], cv[1], sv[1]);
  dst[1] = make_float4(cv[2], sv[2], cv[3], sv[3]);
}

// ---------------- K4: per-patch quadratic forms ev_w = p^T A_w p ----------------
__global__ __launch_bounds__(256) void k_quant(const float* __restrict__ cs, const float* __restrict__ A,
                                               float* __restrict__ q) {
  __shared__ float4 As[4][64];
  int tid = threadIdx.x;
  ((float4*)As)[tid] = ((const float4*)A)[tid];
  __syncthreads();
  size_t p = (size_t)blockIdx.x*256 + tid;
  float4 c01 = ((const float4*)cs)[p*2];
  float4 c23 = ((const float4*)cs)[p*2+1];
  float v0[2] = {c01.x, c01.y}, v1[2] = {c01.z, c01.w};
  float v2[2] = {c23.x, c23.y}, v3[2] = {c23.z, c23.w};
  float pv[16];
#pragma unroll
  for (int i = 0; i < 16; ++i)
    pv[i] = v0[(i>>3)&1] * v1[(i>>2)&1] * v2[(i>>1)&1] * v3[i&1];
  float ev[4];
#pragma unroll
  for (int w = 0; w < 4; ++w) {
    float acc = 0.f;
#pragma unroll
    for (int i = 0; i < 16; ++i) {
      float d = 0.f;
#pragma unroll
      for (int j4 = 0; j4 < 4; ++j4) {
        float4 a = As[w][i*4 + j4];
        d = fmaf(a.x, pv[j4*4+0], d);
        d = fmaf(a.y, pv[j4*4+1], d);
        d = fmaf(a.z, pv[j4*4+2], d);
        d = fmaf(a.w, pv[j4*4+3], d);
      }
      acc = fmaf(pv[i], d, acc);
    }
    ev[w] = acc;
  }
  ((float4*)q)[p] = make_float4(ev[0], ev[1], ev[2], ev[3]);
}

// ---------------- K5: fused FC chain, one wave per batch row ----------------
__global__ __launch_bounds__(256) void k_fc(const float* __restrict__ q, const float* __restrict__ wt,
                                            const float* __restrict__ b1a, const float* __restrict__ b1b,
                                            const float* __restrict__ b2a, const float* __restrict__ b2b,
                                            float* __restrict__ out) {
  __shared__ float sh[4][512];
  int tid = threadIdx.x, wv = tid >> 6, lane = tid & 63;
  int row = blockIdx.x*4 + wv;
  float* S = sh[wv];
  const float4* qr = (const float4*)(q + (size_t)row*256);
  ((float4*)S)[lane] = qr[lane];
  __syncthreads();
  const float* WT1a = wt;
  const float* WT1b = wt + 16384;
  const float* WT2a = wt + 24576;
  const float* WT2b = wt + 32768;
  float acc = b1a[lane];
  for (int j = 0; j < 256; ++j) acc = fmaf(WT1a[j*64+lane], S[j], acc);
  float h = fmaxf(acc, 0.f);
  __syncthreads();
  S[256+lane] = h;
  __syncthreads();
  float a0 = b1b[lane], a1 = b1b[64+lane];
  for (int j = 0; j < 64; ++j) {
    float sj = S[256+j];
    a0 = fmaf(WT1b[j*128+lane],    sj, a0);
    a1 = fmaf(WT1b[j*128+64+lane], sj, a1);
  }
  __syncthreads();
  S[320+lane] = a0; S[384+lane] = a1;
  __syncthreads();
  float c2a = b2a[lane];
  for (int j = 0; j < 128; ++j) c2a = fmaf(WT2a[j*64+lane], S[320+j], c2a);
  float h2v = fmaxf(c2a, 0.f);
  __syncthreads();
  S[448+lane] = h2v;
  __syncthreads();
  if (lane < 10) {
    float o = b2b[lane];
    for (int j = 0; j < 64; ++j) o = fmaf(WT2b[j*10+lane], S[448+j], o);
    out[(size_t)row*10 + lane] = o;
  }
}

extern "C" void kernel_launch(void* const* d_in, const int* in_sizes, int n_in,
                              void* d_out, int out_size, void* d_ws, size_t ws_size,
                              hipStream_t stream) {
  const float* x       = (const float*)d_in[0];
  const float* conv1_w = (const float*)d_in[1];
  const float* conv1_b = (const float*)d_in[2];
  const float* conv2_w = (const float*)d_in[3];
  const float* conv2_b = (const float*)d_in[4];
  const float* conv3_w = (const float*)d_in[5];
  const float* conv3_b = (const float*)d_in[6];
  const float* qw_u3   = (const float*)d_in[7];
  const float* qw_ang  = (const float*)d_in[8];
  const float* fc1a_w  = (const float*)d_in[9];
  const float* fc1a_b  = (const float*)d_in[10];
  const float* fc1b_w  = (const float*)d_in[11];
  const float* fc1b_b  = (const float*)d_in[12];
  const float* fc2a_w  = (const float*)d_in[13];
  const float* fc2a_b  = (const float*)d_in[14];
  const float* fc2b_w  = (const float*)d_in[15];
  const float* fc2b_b  = (const float*)d_in[16];
  float* out = (float*)d_out;

  float* ws = (float*)d_ws;
  float* A   = ws;                      // 1024 floats
  float* WT  = ws + 1024;               // 33408 floats
  float* h1  = ws + 34816;              // 16777216 floats (1024x64x16x16)
  float* h2  = ws + 16812032;           // 1048576 floats  (1024x16x8x8)
  float* cs  = ws + 17860608;           // 524288 floats   (65536x8)
  float* q   = ws + 18384896;           // 262144 floats   (1024x256)

  k_qmat <<<1,    256, 0, stream>>>(qw_u3, qw_ang, A);
  k_trans<<<131,  256, 0, stream>>>(fc1a_w, fc1b_w, fc2a_w, fc2b_w, WT);
  k_conv1<<<1024, 256, 0, stream>>>(x, conv1_w, conv1_b, h1);
  k_conv2<<<1024, 256, 0, stream>>>(h1, conv2_w, conv2_b, h2);
  k_conv3<<<256,  256, 0, stream>>>(h2, conv3_w, conv3_b, cs);
  k_quant<<<256,  256, 0, stream>>>(cs, A, q);
  k_fc   <<<256,  256, 0, stream>>>(q, WT, fc1a_b, fc1b_b, fc2a_b, fc2b_b, out);
}